// Round 4
// baseline (395.814 us; speedup 1.0000x reference)
//
#include <hip/hip_runtime.h>

typedef unsigned short u16;
typedef unsigned int   u32;
typedef _Float16 half2_t __attribute__((ext_vector_type(2)));
typedef _Float16 f16x8  __attribute__((ext_vector_type(8)));
typedef float    f32x16 __attribute__((ext_vector_type(16)));
typedef float    f32x4  __attribute__((ext_vector_type(4)));
typedef unsigned u32x4  __attribute__((ext_vector_type(4)));
typedef unsigned u32x2  __attribute__((ext_vector_type(2)));

// packed-weight layout inside d_ws (u32 word indices, after the agg region)
#define W1T_OFF   0        // [t][mt][kc][lane][4] MFMA A-frags of W1^T (f16 pairs)
#define W2T_OFF   4096
#define B1F_OFF   8192     // [t][mt][lane] bias A-frag word (lane<32: f16(b1) in low half)
#define B2F_OFF   8448
#define NWO1_OFF  8704     // node MLP: [48][64] f16-pairs over k
#define NWO2_OFF  11776    // [32][64]
#define NWO3_OFF  13824    // [32][32]
#define NB_OFF    14848    // floats: bo1[64] bo2[64] bo3[32]
#define PW_WORDS  15008

__device__ __forceinline__ u16 f2h_bits(float f){ _Float16 h=(_Float16)f; return __builtin_bit_cast(u16,h); }
__device__ __forceinline__ half2_t h2u(u32 u){ return __builtin_bit_cast(half2_t,u); }

__device__ __forceinline__ u32 pkrtz(float a, float b){
#if defined(__has_builtin)
#if __has_builtin(__builtin_amdgcn_cvt_pkrtz)
  auto r = __builtin_amdgcn_cvt_pkrtz(a,b);
  return __builtin_bit_cast(u32, r);
#else
  return (u32)f2h_bits(a) | ((u32)f2h_bits(b)<<16);
#endif
#else
  return (u32)f2h_bits(a) | ((u32)f2h_bits(b)<<16);
#endif
}

// permlane32_swap: out0 = {a.lo32, b.lo32}, out1 = {a.hi32, b.hi32}
__device__ __forceinline__ u32x2 plswap(u32 a, u32 b){
#if defined(__has_builtin)
#if __has_builtin(__builtin_amdgcn_permlane32_swap)
  return __builtin_amdgcn_permlane32_swap(a, b, false, false);
#else
  u32 pa = (u32)__shfl_xor((int)a, 32);
  u32 pb = (u32)__shfl_xor((int)b, 32);
  int hh = (int)((threadIdx.x & 63) >> 5);
  u32x2 r; r[0] = hh ? pb : a; r[1] = hh ? b : pa; return r;
#endif
#else
  u32 pa = (u32)__shfl_xor((int)a, 32);
  u32 pb = (u32)__shfl_xor((int)b, 32);
  int hh = (int)((threadIdx.x & 63) >> 5);
  u32x2 r; r[0] = hh ? pb : a; r[1] = hh ? b : pa; return r;
#endif
}

#define MFMA(A,B,C) __builtin_amdgcn_mfma_f32_32x32x16_f16((A),(B),(C),0,0,0)

#if defined(__has_builtin)
#if __has_builtin(__builtin_amdgcn_fdot2)
#define FDOT2(a,b,c) __builtin_amdgcn_fdot2((a),(b),(c),false)
#endif
#endif
#ifndef FDOT2
#define FDOT2(a,b,c) (fmaf((float)(a)[1],(float)(b)[1], fmaf((float)(a)[0],(float)(b)[0],(c))))
#endif

// ---------------- prep: pack weights into MFMA frag / dot2 layouts ------------------
__global__ void prep_kernel(const float* __restrict__ W1, const float* __restrict__ b1,
                            const float* __restrict__ W2, const float* __restrict__ b2,
                            const float* __restrict__ Wo1, const float* __restrict__ bo1,
                            const float* __restrict__ Wo2, const float* __restrict__ bo2,
                            const float* __restrict__ Wo3, const float* __restrict__ bo3,
                            u32* __restrict__ pw)
{
  int i = blockIdx.x*blockDim.x + threadIdx.x;
  for (; i < PW_WORDS; i += gridDim.x*blockDim.x) {
    if (i < 4096) {                         // W1^T A-frags
      int r=i&3, lane=(i>>2)&63, kc=(i>>8)&3, mt=(i>>10)&1, t=(i>>11)&1;
      int h=lane>>5, feat=mt*32+(lane&31);
      int k0=kc*16 + h*8 + 2*r;
      float lo=W1[t*4096 + k0*64 + feat], hi=W1[t*4096 + (k0+1)*64 + feat];
      pw[W1T_OFF+i] = (u32)f2h_bits(lo) | ((u32)f2h_bits(hi)<<16);
    } else if (i < 8192) {                  // W2^T A-frags
      int q=i-4096;
      int r=q&3, lane=(q>>2)&63, kc=(q>>8)&3, mt=(q>>10)&1, t=(q>>11)&1;
      int h=lane>>5, feat=mt*32+(lane&31);
      int k0=kc*16 + h*8 + 2*r;
      float lo=W2[t*4096 + k0*64 + feat], hi=W2[t*4096 + (k0+1)*64 + feat];
      pw[i] = (u32)f2h_bits(lo) | ((u32)f2h_bits(hi)<<16);
    } else if (i < 8448) {                  // b1 bias frag word
      int q=i-8192; int lane=q&63, mt=(q>>6)&1, t=(q>>7)&1;
      pw[i] = (lane<32) ? (u32)f2h_bits(b1[t*64 + mt*32 + (lane&31)]) : 0u;
    } else if (i < 8704) {                  // b2 bias frag word
      int q=i-8448; int lane=q&63, mt=(q>>6)&1, t=(q>>7)&1;
      pw[i] = (lane<32) ? (u32)f2h_bits(b2[t*64 + mt*32 + (lane&31)]) : 0u;
    } else if (i < 11776) {                 // node Wo1 [48 kk][64 j]
      int q=i-NWO1_OFF, kk=q>>6, j=q&63;
      pw[i] = (u32)f2h_bits(Wo1[(2*kk)*64 + j]) | ((u32)f2h_bits(Wo1[(2*kk+1)*64 + j])<<16);
    } else if (i < 13824) {                 // node Wo2 [32][64]
      int q=i-NWO2_OFF, kk=q>>6, j=q&63;
      pw[i] = (u32)f2h_bits(Wo2[(2*kk)*64 + j]) | ((u32)f2h_bits(Wo2[(2*kk+1)*64 + j])<<16);
    } else if (i < 14848) {                 // node Wo3 [32][32]
      int q=i-NWO3_OFF, kk=q>>5, j=q&31;
      pw[i] = (u32)f2h_bits(Wo3[(2*kk)*32 + j]) | ((u32)f2h_bits(Wo3[(2*kk+1)*32 + j])<<16);
    } else {                                // node biases f32
      int q = i - NB_OFF;
      float* nb = (float*)(pw + NB_OFF);
      float v;
      if (q < 64)       v = bo1[q];
      else if (q < 128) v = bo2[q-64];
      else              v = bo3[q-128];
      nb[q] = v;
    }
  }
}

// one edge-type's 2-layer MLP on 32 edges (swapped-operand MFMA). T is a literal.
#define EDGE_TYPE(T, PT, FIRST) do{                                          \
    f32x16 accA_[2];                                                         \
    _Pragma("unroll")                                                        \
    for (int mt=0; mt<2; ++mt){                                              \
      f16x8 Ab_ = __builtin_bit_cast(f16x8,(u32x4){ b1w[T][mt],0u,0u,0u });  \
      f32x16 a_ = MFMA(Ab_, Bb, zacc);                                       \
      _Pragma("unroll")                                                      \
      for (int kc=0;kc<4;kc++) a_ = MFMA(w1f[T][mt][kc], bfrag[kc], a_);     \
      accA_[mt] = a_;                                                        \
    }                                                                        \
    u32 pk_[2][8];                                                           \
    _Pragma("unroll")                                                        \
    for (int mt=0; mt<2; ++mt)                                               \
      _Pragma("unroll")                                                      \
      for (int p=0;p<8;p++)                                                  \
        pk_[mt][p] = pkrtz(fmaxf(accA_[mt][2*p],0.f),                        \
                           fmaxf(accA_[mt][2*p+1],0.f));                     \
    f16x8 b2f_[4];                                                           \
    _Pragma("unroll")                                                        \
    for (int kc=0;kc<4;kc++){                                                \
      int ms_=kc>>1, A_=(kc&1)*4;                                            \
      u32x2 s0_=plswap(pk_[ms_][A_+0],pk_[ms_][A_+2]);                       \
      u32x2 s1_=plswap(pk_[ms_][A_+1],pk_[ms_][A_+3]);                       \
      b2f_[kc]=__builtin_bit_cast(f16x8,(u32x4){s0_[0],s1_[0],s0_[1],s1_[1]});\
    }                                                                        \
    _Pragma("unroll")                                                        \
    for (int mt=0; mt<2; ++mt){                                              \
      f16x8 Ab2_=__builtin_bit_cast(f16x8,(u32x4){ b2w[T][mt],0u,0u,0u });   \
      f32x16 c_=MFMA(Ab2_, Bb, zacc);                                        \
      _Pragma("unroll")                                                      \
      for (int kc=0;kc<4;kc++) c_=MFMA(w2f[T][mt][kc], b2f_[kc], c_);        \
      _Pragma("unroll")                                                      \
      for (int i=0;i<16;i++){                                                \
        float v_=(PT)*fmaxf(c_[i],0.f);                                      \
        if (FIRST) msg[mt][i]=v_; else msg[mt][i]+=v_;                       \
      }                                                                      \
    }                                                                        \
  } while(0)

// ---------------- edge kernel: 32 edges/wave-iter, software-pipelined ---------------
__global__ __launch_bounds__(256,2) void edge_kernel(
    const float* __restrict__ x, const float* __restrict__ ep,
    const int* __restrict__ eidx, const u32* __restrict__ pw,
    float* __restrict__ agg, int E)
{
  const int wid = threadIdx.x>>6, lane = threadIdx.x&63;
  const int h = lane>>5, e32 = lane&31;
  const int gwave = blockIdx.x*4 + wid;
  const long step = (long)gridDim.x*4*32;

  __shared__ float msg_lds[4][32*66];
  float* ml = msg_lds[wid];

  const u32x4* pw4 = (const u32x4*)pw;
  f16x8 w1f[2][2][4], w2f[2][2][4];
#pragma unroll
  for (int t=0;t<2;t++)
#pragma unroll
   for (int mt=0;mt<2;mt++)
#pragma unroll
    for (int kc=0;kc<4;kc++){
      w1f[t][mt][kc] = __builtin_bit_cast(f16x8, pw4[(W1T_OFF>>2) + ((t*2+mt)*4+kc)*64 + lane]);
      w2f[t][mt][kc] = __builtin_bit_cast(f16x8, pw4[(W2T_OFF>>2) + ((t*2+mt)*4+kc)*64 + lane]);
    }
  u32 b1w[2][2], b2w[2][2];
#pragma unroll
  for (int t=0;t<2;t++)
#pragma unroll
   for (int mt=0;mt<2;mt++){
     b1w[t][mt] = pw[B1F_OFF + t*128 + mt*64 + lane];
     b2w[t][mt] = pw[B2F_OFF + t*128 + mt*64 + lane];
   }
  const f16x8 Bb = __builtin_bit_cast(f16x8, (u32x4){ (h==0)?0x3C00u:0u, 0u, 0u, 0u });
  f32x16 zacc;
#pragma unroll
  for (int i=0;i<16;i++) zacc[i]=0.f;

  long base = (long)gwave*32;
  if (base >= (long)E) return;

  // prologue: meta + raw x-gather for first group
  int rv, cv; float p0, p1;
  {
    bool eok = (base + e32) < (long)E;
    long ei  = eok ? (base + e32) : 0;
    rv = eidx[ei]; cv = eidx[(long)E + ei];
    p0 = eok ? ep[ei] : 0.f; p1 = eok ? ep[(long)E + ei] : 0.f;
  }
  f32x4 ga[8];
#pragma unroll
  for (int kc=0;kc<4;kc++){
    int node = (kc<2) ? rv : cv;
    const f32x4* xp = (const f32x4*)(x + ((size_t)node<<5) + ((kc&1)<<4) + (h<<3));
    ga[2*kc] = xp[0]; ga[2*kc+1] = xp[1];
  }

  for (;;){
    long nbase = base + step;
    bool have_next = nbase < (long)E;
    int nrv=0, ncv=0; float np0=0.f, np1=0.f;
    if (have_next){                       // issue next meta early
      bool eok = (nbase + e32) < (long)E;
      long ei  = eok ? (nbase + e32) : 0;
      nrv = eidx[ei]; ncv = eidx[(long)E + ei];
      np0 = eok ? ep[ei] : 0.f; np1 = eok ? ep[(long)E + ei] : 0.f;
    }

    // convert current raw gather -> f16 B-frags (pre_msg^T)
    f16x8 bfrag[4];
#pragma unroll
    for (int kc=0;kc<4;kc++){
      f32x4 a = ga[2*kc], b = ga[2*kc+1];
      bfrag[kc] = __builtin_bit_cast(f16x8, (u32x4){ pkrtz(a[0],a[1]), pkrtz(a[2],a[3]),
                                                     pkrtz(b[0],b[1]), pkrtz(b[2],b[3]) });
    }

    float msg[2][16];
    EDGE_TYPE(0, p0, true);               // type-0 MLP

    if (have_next){                       // issue next x-gather; consumed next iter
#pragma unroll
      for (int kc=0;kc<4;kc++){
        int node = (kc<2) ? nrv : ncv;
        const f32x4* xp = (const f32x4*)(x + ((size_t)node<<5) + ((kc&1)<<4) + (h<<3));
        ga[2*kc] = xp[0]; ga[2*kc+1] = xp[1];
      }
    }

    EDGE_TYPE(1, p1, false);              // type-1 MLP (accumulate)

    // transpose [feat][edge] -> [edge][feat] via padded LDS, then contiguous atomics
#pragma unroll
    for (int mt=0;mt<2;mt++)
#pragma unroll
     for (int p=0;p<8;p++){
       int feat = mt*32 + ((2*p)&3) + 8*(p>>1) + 4*h;
       float2 val; val.x = msg[mt][2*p]; val.y = msg[mt][2*p+1];
       *(float2*)(ml + e32*66 + feat) = val;
     }
    asm volatile("s_waitcnt lgkmcnt(0)" ::: "memory");
#pragma unroll
    for (int e=0;e<32;e++){
      int re = __shfl(rv, e);
      float v = ml[e*66 + lane];
      atomicAdd(&agg[((size_t)re<<6) + lane], v);  // adds 0 for padded edges
    }

    if (!have_next) break;
    base = nbase; rv = nrv; cv = ncv; p0 = np0; p1 = np1;
  }
}

// ---------------- node kernel: persistent waves, lane = output feature --------------
__global__ __launch_bounds__(256,2) void node_kernel(
    const float* __restrict__ x, const float* __restrict__ agg,
    const u32* __restrict__ pw, float* __restrict__ out, int N)
{
  const int wid=threadIdx.x>>6, lane=threadIdx.x&63;
  const int gwave = blockIdx.x*4 + wid;
  const int nwaves = gridDim.x*4;
  __shared__ __align__(16) u16 aug_lds[4][96];
  __shared__ __align__(16) u16 h_lds[4][64];

  u32 wo1r[48], wo2r[32], wo3r[32];
#pragma unroll
  for (int kk=0;kk<48;++kk) wo1r[kk]=pw[NWO1_OFF + kk*64 + lane];
#pragma unroll
  for (int kk=0;kk<32;++kk) wo2r[kk]=pw[NWO2_OFF + kk*64 + lane];
#pragma unroll
  for (int kk=0;kk<32;++kk) wo3r[kk]=pw[NWO3_OFF + kk*32 + (lane&31)];
  const float* nb=(const float*)(pw+NB_OFF);
  float bo1r=nb[lane], bo2r=nb[64+lane], bo3r=nb[128+(lane&31)];

  for (int node = gwave; node < N; node += nwaves){
    float xv=0.f;
    if (lane<32){ xv=x[(size_t)node*32+lane]; aug_lds[wid][lane]=f2h_bits(xv); }
    aug_lds[wid][32+lane]=f2h_bits(agg[(size_t)node*64+lane]);

    const half2_t* aug2=(const half2_t*)aug_lds[wid];
    float s0=bo1r,s1=0.f,s2=0.f,s3=0.f;
#pragma unroll
    for (int kk=0;kk<48;kk+=4){
      s0=FDOT2(aug2[kk+0],h2u(wo1r[kk+0]),s0);
      s1=FDOT2(aug2[kk+1],h2u(wo1r[kk+1]),s1);
      s2=FDOT2(aug2[kk+2],h2u(wo1r[kk+2]),s2);
      s3=FDOT2(aug2[kk+3],h2u(wo1r[kk+3]),s3);
    }
    h_lds[wid][lane]=f2h_bits(fmaxf((s0+s1)+(s2+s3),0.f));
    const half2_t* hp=(const half2_t*)h_lds[wid];
    float t0=bo2r,t1=0.f,t2=0.f,t3=0.f;
#pragma unroll
    for (int kk=0;kk<32;kk+=4){
      t0=FDOT2(hp[kk+0],h2u(wo2r[kk+0]),t0);
      t1=FDOT2(hp[kk+1],h2u(wo2r[kk+1]),t1);
      t2=FDOT2(hp[kk+2],h2u(wo2r[kk+2]),t2);
      t3=FDOT2(hp[kk+3],h2u(wo2r[kk+3]),t3);
    }
    float h2v=fmaxf((t0+t1)+(t2+t3),0.f);
    h_lds[wid][lane]=f2h_bits(h2v);   // same-wave in-order LDS: reads above already done
    if (lane<32){
      float r0=bo3r,r1=0.f,r2=0.f,r3=0.f;
#pragma unroll
      for (int kk=0;kk<32;kk+=4){
        r0=FDOT2(hp[kk+0],h2u(wo3r[kk+0]),r0);
        r1=FDOT2(hp[kk+1],h2u(wo3r[kk+1]),r1);
        r2=FDOT2(hp[kk+2],h2u(wo3r[kk+2]),r2);
        r3=FDOT2(hp[kk+3],h2u(wo3r[kk+3]),r3);
      }
      out[(size_t)node*32+lane]=((r0+r1)+(r2+r3))+xv;
    }
  }
}

extern "C" void kernel_launch(void* const* d_in, const int* in_sizes, int n_in,
                              void* d_out, int out_size, void* d_ws, size_t ws_size,
                              hipStream_t stream)
{
  const float* x   = (const float*)d_in[0];
  const float* ep  = (const float*)d_in[1];
  const float* W1  = (const float*)d_in[2];
  const float* b1  = (const float*)d_in[3];
  const float* W2  = (const float*)d_in[4];
  const float* b2  = (const float*)d_in[5];
  const float* Wo1 = (const float*)d_in[6];
  const float* bo1 = (const float*)d_in[7];
  const float* Wo2 = (const float*)d_in[8];
  const float* bo2 = (const float*)d_in[9];
  const float* Wo3 = (const float*)d_in[10];
  const float* bo3 = (const float*)d_in[11];
  const int* eidx  = (const int*)d_in[12];

  int N = in_sizes[0]/32;
  int E = in_sizes[12]/2;

  float* agg = (float*)d_ws;
  u32*   pw  = (u32*)((char*)d_ws + (size_t)N*64*sizeof(float));

  hipMemsetAsync(agg, 0, (size_t)N*64*sizeof(float), stream);
  prep_kernel<<<64, 256, 0, stream>>>(W1,b1,W2,b2,Wo1,bo1,Wo2,bo2,Wo3,bo3,pw);

  edge_kernel<<<1024, 256, 0, stream>>>(x, ep, eidx, pw, agg, E);
  node_kernel<<<1024, 256, 0, stream>>>(x, agg, pw, (float*)d_out, N);
}